// Round 1
// baseline (507.538 us; speedup 1.0000x reference)
//
#include <hip/hip_runtime.h>
#include <hip/hip_fp16.h>

typedef _Float16 half8 __attribute__((ext_vector_type(8)));
typedef float floatx4 __attribute__((ext_vector_type(4)));

#define R_TOT   131072      // rows per tensor (2*16*4096)
#define OUT_SC  33554432    // scalar losses start (after K_mix + V_mix)
#define OUT_USE 33554436    // usage_k start
#define WS_C2   524288      // byte offset of c2 arrays in ws

// ws layout (bytes):
//   0        cbh_k   512*128 f16, MFMA B-fragment order: half8[(nt*4+s)*64+lane]
//            where value = cb[code=nt*16+(lane&15)][k=s*32+(lane>>4)*8+j]
//   131072   cbl_k   (residual * 2048, f16), same order
//   262144   cbh_v
//   393216   cbl_v
//   524288   c2_k[512], c2_v[512]  fp32

__global__ void vq_init(const float* __restrict__ cb_k, const float* __restrict__ cb_v,
                        float* __restrict__ out, char* __restrict__ ws) {
    const int b = blockIdx.x, t = threadIdx.x;   // 256 threads
    if (b < 64) {
        const int tensor = b >> 5, nt = b & 31;
        const int s = t >> 6, lane = t & 63, l15 = lane & 15, quad = lane >> 4;
        const float* cb = tensor ? cb_v : cb_k;
        half8* wsh = (half8*)(ws + (size_t)tensor * 262144);
        half8* wsl = wsh + 8192;
        const int code = nt * 16 + l15;
        const float* src = cb + code * 128 + s * 32 + quad * 8;
        float4 z0 = *(const float4*)src;
        float4 z1 = *(const float4*)(src + 4);
        float zz[8] = {z0.x, z0.y, z0.z, z0.w, z1.x, z1.y, z1.z, z1.w};
        half8 h, l;
        float p = 0.0f;
        #pragma unroll
        for (int j = 0; j < 8; ++j) {
            _Float16 hi = (_Float16)zz[j];
            h[j] = hi;
            l[j] = (_Float16)((zz[j] - (float)hi) * 2048.0f);  // scaled: avoid f16 denormals
            p = fmaf(zz[j], zz[j], p);
        }
        wsh[(nt * 4 + s) * 64 + lane] = h;
        wsl[(nt * 4 + s) * 64 + lane] = l;
        // c2: reduce over quad within wave, then deterministic cross-wave (s) sum
        p += __shfl_xor(p, 16);
        p += __shfl_xor(p, 32);
        __shared__ float c2p[4][16];
        if (lane < 16) c2p[s][lane] = p;
        __syncthreads();
        if (t < 16)
            ((float*)(ws + WS_C2))[tensor * 512 + nt * 16 + t] =
                ((c2p[0][t] + c2p[1][t]) + c2p[2][t]) + c2p[3][t];
    } else {
        // zero scalar losses (4) + usage (1024): harness poisons d_out each call
        int i = (b - 64) * 256 + t;
        if (i < 1028) out[OUT_SC + i] = 0.0f;
    }
}

// Async global->LDS DMA, 16B per lane; LDS dest must be linear (uniform base + lane*16).
__device__ __forceinline__ void gload_lds16(const void* g, void* l) {
    __builtin_amdgcn_global_load_lds(
        (const __attribute__((address_space(1))) void*)g,
        (__attribute__((address_space(3))) void*)l, 16, 0, 0);
}

// Block: 256 threads (4 waves), 128 rows; wave: 32 rows (2 m-tiles of 16).
// K-loop: B-fragments staged ONCE PER BLOCK into LDS (double-buffered chunks of
// 2 n-tiles = 16 KB) via global_load_lds DMA issued a full chunk (~700+ cyc of
// MFMA) ahead; waves consume via contiguous ds_read_b128. This removes the 4x
// redundant per-wave L2 fragment streaming and the per-iteration vmcnt stall of
// the register-double-buffered version. c2 lives in LDS (loaded once).
__global__ __launch_bounds__(256, 4)
void vq_main(const float* __restrict__ Kp, const float* __restrict__ Vp,
             const float* __restrict__ cb_k, const float* __restrict__ cb_v,
             float* __restrict__ out, char* __restrict__ ws) {
    __shared__ half8 frag[2][1024];   // [dbuf][ hi: 0..511 | lo: 512..1023 ]  32 KB
    __shared__ float c2s[512];
    __shared__ int   lds_idx[128];

    const int tid  = threadIdx.x;
    const int wave = tid >> 6;
    const int lane = tid & 63;
    const int quad = lane >> 4;
    const int l15  = lane & 15;
    const int tensor = blockIdx.y;

    const float* __restrict__ Z   = tensor ? Vp : Kp;
    const float* __restrict__ cbf = tensor ? cb_v : cb_k;
    const half8* __restrict__ gh  = (const half8*)(ws + (size_t)tensor * 262144);
    const half8* __restrict__ gl  = gh + 8192;
    const float* __restrict__ c2g = (const float*)(ws + WS_C2) + tensor * 512;
    float* __restrict__ outz = out + (size_t)tensor * 16777216;

    const int blockRow = blockIdx.x * 128;
    const int waveRow  = blockRow + wave * 32;

    // ---- issue chunk-0 DMA + c2 staging first: latency hides under Phase A ----
    {
        #pragma unroll
        for (int i = 0; i < 2; ++i) {
            const int e = i * 256 + tid;              // element within chunk [0,512)
            gload_lds16(gh + e, &frag[0][e]);
            gload_lds16(gl + e, &frag[0][512 + e]);
        }
        c2s[tid]       = c2g[tid];
        c2s[tid + 256] = c2g[tid + 256];
    }

    // ---- Phase A: load this wave's 32 rows, build A-frags (hi + scaled-lo), row z2 ----
    // (arithmetic order identical to previous rounds -> bit-identical distances)
    half8 ah[2][4], al[2][4];
    float z2r[2][4];
    #pragma unroll
    for (int t = 0; t < 2; ++t) {
        const float* zp = Z + (size_t)(waveRow + t * 16 + l15) * 128;
        float zsq = 0.0f;
        #pragma unroll
        for (int s = 0; s < 4; ++s) {
            const float* p = zp + s * 32 + quad * 8;   // A[m=l15][k=quad*8+j], k-step s*32
            float4 z0 = *(const float4*)p;
            float4 z1 = *(const float4*)(p + 4);
            float zz[8] = {z0.x, z0.y, z0.z, z0.w, z1.x, z1.y, z1.z, z1.w};
            #pragma unroll
            for (int j = 0; j < 8; ++j) {
                _Float16 h = (_Float16)zz[j];
                ah[t][s][j] = h;
                al[t][s][j] = (_Float16)((zz[j] - (float)h) * 2048.0f);
                zsq = fmaf(zz[j], zz[j], zsq);
            }
        }
        zsq += __shfl_xor(zsq, 16);   // sum across quads -> full row z2 on every lane
        zsq += __shfl_xor(zsq, 32);
        #pragma unroll
        for (int r = 0; r < 4; ++r) z2r[t][r] = __shfl(zsq, quad * 4 + r);  // z2 of C-rows
    }

    float bd[2][4];
    int   bi[2][4];
    #pragma unroll
    for (int t = 0; t < 2; ++t)
        #pragma unroll
        for (int r = 0; r < 4; ++r) { bd[t][r] = 3.4e38f; bi[t][r] = 0; }

    // chunk-0 DMA + c2s stores must be visible to all waves
    asm volatile("s_waitcnt vmcnt(0)" ::: "memory");
    __syncthreads();

    // ---- K-loop: 16 chunks x 2 n-tiles; DMA chunk c+1 while computing chunk c ----
    for (int c = 0; c < 16; ++c) {
        const int b = c & 1;
        if (c < 15) {
            #pragma unroll
            for (int i = 0; i < 2; ++i) {
                const int e  = i * 256 + tid;
                const int ge = (c + 1) * 512 + e;
                gload_lds16(gh + ge, &frag[b ^ 1][e]);
                gload_lds16(gl + ge, &frag[b ^ 1][512 + e]);
            }
        }
        #pragma unroll
        for (int ntl = 0; ntl < 2; ++ntl) {
            const int nt = c * 2 + ntl;
            half8 bh[4], bl[4];
            #pragma unroll
            for (int s = 0; s < 4; ++s) {           // contiguous ds_read_b128, conflict-free
                bh[s] = frag[b][(ntl * 4 + s) * 64 + lane];
                bl[s] = frag[b][512 + (ntl * 4 + s) * 64 + lane];
            }
            const float c2v = c2s[nt * 16 + l15];
            floatx4 p10 = {0,0,0,0}, p11 = {0,0,0,0}, p20 = {0,0,0,0}, p21 = {0,0,0,0};
            #pragma unroll
            for (int s = 0; s < 4; ++s) {
                p10 = __builtin_amdgcn_mfma_f32_16x16x32_f16(ah[0][s], bh[s], p10, 0, 0, 0);
                p11 = __builtin_amdgcn_mfma_f32_16x16x32_f16(ah[1][s], bh[s], p11, 0, 0, 0);
                p20 = __builtin_amdgcn_mfma_f32_16x16x32_f16(al[0][s], bh[s], p20, 0, 0, 0);
                p21 = __builtin_amdgcn_mfma_f32_16x16x32_f16(al[1][s], bh[s], p21, 0, 0, 0);
                p20 = __builtin_amdgcn_mfma_f32_16x16x32_f16(ah[0][s], bl[s], p20, 0, 0, 0);
                p21 = __builtin_amdgcn_mfma_f32_16x16x32_f16(ah[1][s], bl[s], p21, 0, 0, 0);
            }
            const int codeg = nt * 16 + l15;
            // Emulate ref fp32 rounding: d = fl( fl(z2+c2) - 2*logit ); ties -> lower idx.
            #pragma unroll
            for (int r = 0; r < 4; ++r) {
                float lg0 = fmaf(p20[r], 0x1p-11f, p10[r]);
                float d0  = fmaf(-2.0f, lg0, z2r[0][r] + c2v);
                if (d0 < bd[0][r]) { bd[0][r] = d0; bi[0][r] = codeg; }
                float lg1 = fmaf(p21[r], 0x1p-11f, p11[r]);
                float d1  = fmaf(-2.0f, lg1, z2r[1][r] + c2v);
                if (d1 < bd[1][r]) { bd[1][r] = d1; bi[1][r] = codeg; }
            }
        }
        if (c < 15) {
            // drain this wave's chunk-(c+1) DMA, then hand buffers over
            asm volatile("s_waitcnt vmcnt(0)" ::: "memory");
            __syncthreads();
        }
    }

    // ---- argmin across the 16 lanes sharing rows; loss = sum(best dist) ----
    float lp = 0.0f;
    #pragma unroll
    for (int t = 0; t < 2; ++t)
        #pragma unroll
        for (int r = 0; r < 4; ++r) {
            float d = bd[t][r];
            int   i = bi[t][r];
            #pragma unroll
            for (int off = 8; off; off >>= 1) {
                float od = __shfl_xor(d, off);
                int   oi = __shfl_xor(i, off);
                if (od < d || (od == d && oi < i)) { d = od; i = oi; }
            }
            if (l15 == 0) {
                lds_idx[wave * 32 + t * 16 + quad * 4 + r] = i;
                lp += d;
            }
        }
    lp += __shfl_xor(lp, 16);
    lp += __shfl_xor(lp, 32);
    if (lane == 0) {
        float p = lp * 0x1p-26f;                   // 0.25 / 16777216
        atomicAdd(&out[OUT_SC + tensor], p);       // beta * commit
        atomicAdd(&out[OUT_SC + 2 + tensor], p);   // gamma * embed (identical in eval)
    }
    __syncthreads();                               // lds_idx ready for all threads

    // ---- fused usage histogram: exact scaled-integer fp32 atomics (count * 2^-17) ----
    if (tid < 128)
        atomicAdd(&out[OUT_USE + tensor * 512 + lds_idx[tid]], 0x1p-17f);

    // ---- Phase C: gather codebook rows (bit-exact fp32 copies), coalesced stores ----
    #pragma unroll
    for (int g = 0; g < 16; ++g) {
        int rl  = g * 8 + (tid >> 5);
        int idx = lds_idx[rl];
        int col = (tid & 31) * 4;
        float4 v = *(const float4*)(cbf + idx * 128 + col);
        *(float4*)(outz + (size_t)(blockRow + rl) * 128 + col) = v;
    }
}

extern "C" void kernel_launch(void* const* d_in, const int* in_sizes, int n_in,
                              void* d_out, int out_size, void* d_ws, size_t ws_size,
                              hipStream_t stream) {
    (void)in_sizes; (void)n_in; (void)out_size; (void)ws_size;
    const float* K   = (const float*)d_in[0];
    const float* V   = (const float*)d_in[1];
    const float* cbk = (const float*)d_in[2];
    const float* cbv = (const float*)d_in[3];
    float* out = (float*)d_out;
    char* ws = (char*)d_ws;
    hipLaunchKernelGGL(vq_init, dim3(69), dim3(256), 0, stream, cbk, cbv, out, ws);
    hipLaunchKernelGGL(vq_main, dim3(1024, 2), dim3(256), 0, stream, K, V, cbk, cbv, out, ws);
}

// Round 2
// 477.832 us; speedup vs baseline: 1.0622x; 1.0622x over previous
//
#include <hip/hip_runtime.h>
#include <hip/hip_fp16.h>

typedef _Float16 half8 __attribute__((ext_vector_type(8)));
typedef float floatx4 __attribute__((ext_vector_type(4)));

#define R_TOT   131072      // rows per tensor (2*16*4096)
#define OUT_SC  33554432    // scalar losses start (after K_mix + V_mix)
#define OUT_USE 33554436    // usage_k start
#define WS_C2   524288      // byte offset of c2 arrays in ws
#define WS_IDX  528384      // byte offset of idx array in ws

// ws layout (bytes):
//   0        cbh_k   512*128 f16, MFMA B-fragment order: half8[(nt*4+s)*64+lane]
//            where value = cb[code=nt*16+(lane&15)][k=s*32+(lane>>4)*8+j]
//   131072   cbl_k   (residual * 2048, f16), same order
//   262144   cbh_v
//   393216   cbl_v
//   524288   c2_k[512], c2_v[512]  fp32
//   528384   idx[2][131072] int

__global__ void vq_init(const float* __restrict__ cb_k, const float* __restrict__ cb_v,
                        float* __restrict__ out, char* __restrict__ ws) {
    const int b = blockIdx.x, t = threadIdx.x;   // 256 threads
    if (b < 64) {
        const int tensor = b >> 5, nt = b & 31;
        const int s = t >> 6, lane = t & 63, l15 = lane & 15, quad = lane >> 4;
        const float* cb = tensor ? cb_v : cb_k;
        half8* wsh = (half8*)(ws + (size_t)tensor * 262144);
        half8* wsl = wsh + 8192;
        const int code = nt * 16 + l15;
        const float* src = cb + code * 128 + s * 32 + quad * 8;
        float4 z0 = *(const float4*)src;
        float4 z1 = *(const float4*)(src + 4);
        float zz[8] = {z0.x, z0.y, z0.z, z0.w, z1.x, z1.y, z1.z, z1.w};
        half8 h, l;
        float p = 0.0f;
        #pragma unroll
        for (int j = 0; j < 8; ++j) {
            _Float16 hi = (_Float16)zz[j];
            h[j] = hi;
            l[j] = (_Float16)((zz[j] - (float)hi) * 2048.0f);  // scaled: avoid f16 denormals
            p = fmaf(zz[j], zz[j], p);
        }
        wsh[(nt * 4 + s) * 64 + lane] = h;
        wsl[(nt * 4 + s) * 64 + lane] = l;
        // c2: reduce over quad within wave, then deterministic cross-wave (s) sum
        p += __shfl_xor(p, 16);
        p += __shfl_xor(p, 32);
        __shared__ float c2p[4][16];
        if (lane < 16) c2p[s][lane] = p;
        __syncthreads();
        if (t < 16)
            ((float*)(ws + WS_C2))[tensor * 512 + nt * 16 + t] =
                ((c2p[0][t] + c2p[1][t]) + c2p[2][t]) + c2p[3][t];
    } else {
        // zero scalar losses (4) + usage (1024): harness poisons d_out each call
        int i = (b - 64) * 256 + t;
        if (i < 1028) out[OUT_SC + i] = 0.0f;
    }
}

// Async global->LDS DMA, 16B per lane; LDS dest is linear (uniform base + lane*16).
__device__ __forceinline__ void gload_lds16(const void* g, void* l) {
    __builtin_amdgcn_global_load_lds(
        (const __attribute__((address_space(1))) void*)g,
        (__attribute__((address_space(3))) void*)l, 16, 0, 0);
}

// Block: 512 threads (8 waves), 256 rows; wave: 32 rows (2 m-tiles of 16).
// Fragment delivery: 3-buffer LDS pipeline of 16 KB chunks (2 n-tiles each),
// DMA'd 2 chunks (~1900 cyc of block compute) ahead via global_load_lds.
// Per chunk: counted s_waitcnt vmcnt(2) (never a full drain until the tail) +
// raw s_barrier. K-loop critical path is pure LDS+MFMA. Fragments are read
// from global ONCE PER BLOCK (256 rows of reuse): 7.5x less fragment traffic
// than the register-streaming version, with 2-period latency cover.
__global__ __launch_bounds__(512, 4)
void vq_main(const float* __restrict__ Kp, const float* __restrict__ Vp,
             const float* __restrict__ cb_k, const float* __restrict__ cb_v,
             float* __restrict__ out, char* __restrict__ ws) {
    __shared__ half8 buf[3][1024];   // 3 x 16 KB chunk buffers [hi:0..511 | lo:512..1023]
    __shared__ float c2s[512];
    __shared__ int   lds_idx[256];

    const int tid  = threadIdx.x;
    const int wave = tid >> 6;
    const int lane = tid & 63;
    const int quad = lane >> 4;
    const int l15  = lane & 15;
    const int tensor = blockIdx.y;

    const float* __restrict__ Z   = tensor ? Vp : Kp;
    const float* __restrict__ cbf = tensor ? cb_v : cb_k;
    const half8* __restrict__ gh  = (const half8*)(ws + (size_t)tensor * 262144);
    const half8* __restrict__ gl  = gh + 8192;
    const float* __restrict__ c2g = (const float*)(ws + WS_C2) + tensor * 512;
    int* __restrict__ idxg = (int*)(ws + WS_IDX) + tensor * R_TOT;
    float* __restrict__ outz = out + (size_t)tensor * 16777216;

    const int blockRow = blockIdx.x * 256;
    const int waveRow  = blockRow + wave * 32;

    // ---- prologue: DMA chunks 0,1 + stage c2; latency hides under Phase A ----
    gload_lds16(gh + tid,       &buf[0][tid]);
    gload_lds16(gl + tid,       &buf[0][512 + tid]);
    gload_lds16(gh + 512 + tid, &buf[1][tid]);
    gload_lds16(gl + 512 + tid, &buf[1][512 + tid]);
    c2s[tid] = c2g[tid];

    // ---- Phase A: load this wave's 32 rows, build A-frags (hi + scaled-lo), row z2 ----
    // (arithmetic order identical to previous rounds -> bit-identical distances)
    half8 ah[2][4], al[2][4];
    float z2r[2][4];
    #pragma unroll
    for (int t = 0; t < 2; ++t) {
        const float* zp = Z + (size_t)(waveRow + t * 16 + l15) * 128;
        float zsq = 0.0f;
        #pragma unroll
        for (int s = 0; s < 4; ++s) {
            const float* p = zp + s * 32 + quad * 8;   // A[m=l15][k=quad*8+j], k-step s*32
            float4 z0 = *(const float4*)p;
            float4 z1 = *(const float4*)(p + 4);
            float zz[8] = {z0.x, z0.y, z0.z, z0.w, z1.x, z1.y, z1.z, z1.w};
            #pragma unroll
            for (int j = 0; j < 8; ++j) {
                _Float16 h = (_Float16)zz[j];
                ah[t][s][j] = h;
                al[t][s][j] = (_Float16)((zz[j] - (float)h) * 2048.0f);
                zsq = fmaf(zz[j], zz[j], zsq);
            }
        }
        zsq += __shfl_xor(zsq, 16);   // sum across quads -> full row z2 on every lane
        zsq += __shfl_xor(zsq, 32);
        #pragma unroll
        for (int r = 0; r < 4; ++r) z2r[t][r] = __shfl(zsq, quad * 4 + r);  // z2 of C-rows
    }

    float bd[2][4];
    int   bi[2][4];
    #pragma unroll
    for (int t = 0; t < 2; ++t)
        #pragma unroll
        for (int r = 0; r < 4; ++r) { bd[t][r] = 3.4e38f; bi[t][r] = 0; }

    // c2s LDS stores drained before the first barrier publishes them
    asm volatile("s_waitcnt lgkmcnt(0)" ::: "memory");

    // ---- K-loop: 16 chunks x 2 n-tiles; chunk c+2 DMA'd while computing chunk c ----
    int cur = 0;
    for (int c = 0; c < 16; ++c) {
        // wait own share of chunk c (oldest 2 VMEM ops); chunk c+1 stays in flight
        if (c < 15) asm volatile("s_waitcnt vmcnt(2)" ::: "memory");
        else        asm volatile("s_waitcnt vmcnt(0)" ::: "memory");
        asm volatile("s_barrier" ::: "memory");   // all waves' chunk-c DMA landed
        if (c < 14) {                             // issue chunk c+2 into the freed buffer
            int nb = cur + 2; if (nb >= 3) nb -= 3;
            gload_lds16(gh + (c + 2) * 512 + tid, &buf[nb][tid]);
            gload_lds16(gl + (c + 2) * 512 + tid, &buf[nb][512 + tid]);
        }
        #pragma unroll
        for (int ntl = 0; ntl < 2; ++ntl) {
            const int nt = c * 2 + ntl;
            half8 bh[4], bl[4];
            #pragma unroll
            for (int s = 0; s < 4; ++s) {         // contiguous ds_read_b128, conflict-free
                bh[s] = buf[cur][(ntl * 4 + s) * 64 + lane];
                bl[s] = buf[cur][512 + (ntl * 4 + s) * 64 + lane];
            }
            const float c2v = c2s[nt * 16 + l15];
            floatx4 p10 = {0,0,0,0}, p11 = {0,0,0,0}, p20 = {0,0,0,0}, p21 = {0,0,0,0};
            #pragma unroll
            for (int s = 0; s < 4; ++s) {
                p10 = __builtin_amdgcn_mfma_f32_16x16x32_f16(ah[0][s], bh[s], p10, 0, 0, 0);
                p11 = __builtin_amdgcn_mfma_f32_16x16x32_f16(ah[1][s], bh[s], p11, 0, 0, 0);
                p20 = __builtin_amdgcn_mfma_f32_16x16x32_f16(al[0][s], bh[s], p20, 0, 0, 0);
                p21 = __builtin_amdgcn_mfma_f32_16x16x32_f16(al[1][s], bh[s], p21, 0, 0, 0);
                p20 = __builtin_amdgcn_mfma_f32_16x16x32_f16(ah[0][s], bl[s], p20, 0, 0, 0);
                p21 = __builtin_amdgcn_mfma_f32_16x16x32_f16(ah[1][s], bl[s], p21, 0, 0, 0);
            }
            const int codeg = nt * 16 + l15;
            // Emulate ref fp32 rounding: d = fl( fl(z2+c2) - 2*logit ); ties -> lower idx.
            #pragma unroll
            for (int r = 0; r < 4; ++r) {
                float lg0 = fmaf(p20[r], 0x1p-11f, p10[r]);
                float d0  = fmaf(-2.0f, lg0, z2r[0][r] + c2v);
                if (d0 < bd[0][r]) { bd[0][r] = d0; bi[0][r] = codeg; }
                float lg1 = fmaf(p21[r], 0x1p-11f, p11[r]);
                float d1  = fmaf(-2.0f, lg1, z2r[1][r] + c2v);
                if (d1 < bd[1][r]) { bd[1][r] = d1; bi[1][r] = codeg; }
            }
        }
        cur += 1; if (cur >= 3) cur -= 3;
    }

    // ---- argmin across the 16 lanes sharing rows; loss = sum(best dist) ----
    float lp = 0.0f;
    #pragma unroll
    for (int t = 0; t < 2; ++t)
        #pragma unroll
        for (int r = 0; r < 4; ++r) {
            float d = bd[t][r];
            int   i = bi[t][r];
            #pragma unroll
            for (int off = 8; off; off >>= 1) {
                float od = __shfl_xor(d, off);
                int   oi = __shfl_xor(i, off);
                if (od < d || (od == d && oi < i)) { d = od; i = oi; }
            }
            if (l15 == 0) {
                lds_idx[wave * 32 + t * 16 + quad * 4 + r] = i;
                lp += d;
            }
        }
    lp += __shfl_xor(lp, 16);
    lp += __shfl_xor(lp, 32);
    if (lane == 0) {
        float p = lp * 0x1p-26f;                   // 0.25 / 16777216
        atomicAdd(&out[OUT_SC + tensor], p);       // beta * commit
        atomicAdd(&out[OUT_SC + 2 + tensor], p);   // gamma * embed (identical in eval)
    }
    __syncthreads();                               // lds_idx ready for all threads

    if (tid < 256) idxg[blockRow + tid] = lds_idx[tid];

    // ---- Phase C: gather codebook rows (bit-exact fp32 copies), coalesced stores ----
    #pragma unroll
    for (int g = 0; g < 16; ++g) {
        int rl  = g * 16 + (tid >> 5);
        int idx = lds_idx[rl];
        int col = (tid & 31) * 4;
        float4 v = *(const float4*)(cbf + idx * 128 + col);
        *(float4*)(outz + (size_t)(blockRow + rl) * 128 + col) = v;
    }
}

__global__ void vq_hist(const int* __restrict__ idxg, float* __restrict__ out) {
    __shared__ int h[512];
    const int tid = threadIdx.x;                 // 256
    const int tensor = blockIdx.x >> 6;
    const int seg = blockIdx.x & 63;
    h[tid] = 0; h[tid + 256] = 0;
    __syncthreads();
    const int* p = idxg + tensor * R_TOT + seg * 2048;
    #pragma unroll
    for (int r = 0; r < 8; ++r) atomicAdd(&h[p[r * 256 + tid]], 1);
    __syncthreads();
    int c0 = h[tid], c1 = h[tid + 256];
    // usage = count * 2^-17: exact scaled-integer fp32 sums
    if (c0) atomicAdd(&out[OUT_USE + tensor * 512 + tid], (float)c0 * 0x1p-17f);
    if (c1) atomicAdd(&out[OUT_USE + tensor * 512 + tid + 256], (float)c1 * 0x1p-17f);
}

extern "C" void kernel_launch(void* const* d_in, const int* in_sizes, int n_in,
                              void* d_out, int out_size, void* d_ws, size_t ws_size,
                              hipStream_t stream) {
    (void)in_sizes; (void)n_in; (void)out_size; (void)ws_size;
    const float* K   = (const float*)d_in[0];
    const float* V   = (const float*)d_in[1];
    const float* cbk = (const float*)d_in[2];
    const float* cbv = (const float*)d_in[3];
    float* out = (float*)d_out;
    char* ws = (char*)d_ws;
    hipLaunchKernelGGL(vq_init, dim3(69), dim3(256), 0, stream, cbk, cbv, out, ws);
    hipLaunchKernelGGL(vq_main, dim3(512, 2), dim3(512), 0, stream, K, V, cbk, cbv, out, ws);
    hipLaunchKernelGGL(vq_hist, dim3(128), dim3(256), 0, stream, (const int*)(ws + WS_IDX), out);
}

// Round 3
// 325.957 us; speedup vs baseline: 1.5571x; 1.4659x over previous
//
#include <hip/hip_runtime.h>
#include <hip/hip_fp16.h>

typedef _Float16 half8 __attribute__((ext_vector_type(8)));
typedef float floatx4 __attribute__((ext_vector_type(4)));

#define R_TOT   131072      // rows per tensor (2*16*4096)
#define OUT_SC  33554432    // scalar losses start (after K_mix + V_mix)
#define OUT_USE 33554436    // usage_k start
#define WS_C2   524288      // byte offset of c2 arrays in ws
#define WS_IDX  528384      // byte offset of idx array in ws
#define WS_LOSS 1576960     // byte offset of per-block loss partials (2*2048 fp32)

// ws layout (bytes):
//   0        cbh_k   512*128 f16, MFMA B-fragment order: half8[(nt*4+s)*64+lane]
//            where value = cb[code=nt*16+(lane&15)][k=s*32+(lane>>4)*8+j]
//   131072   cbl_k   (residual * 2048, f16), same order
//   262144   cbh_v
//   393216   cbl_v
//   524288   c2_k[512], c2_v[512]  fp32
//   528384   idx[2][131072] int
//   1576960  loss partials [2][2048] fp32   (plain stores, no atomics)

__global__ void vq_init(const float* __restrict__ cb_k, const float* __restrict__ cb_v,
                        float* __restrict__ out, char* __restrict__ ws) {
    const int b = blockIdx.x, t = threadIdx.x;   // 256 threads
    if (b < 64) {
        const int tensor = b >> 5, nt = b & 31;
        const int s = t >> 6, lane = t & 63, l15 = lane & 15, quad = lane >> 4;
        const float* cb = tensor ? cb_v : cb_k;
        half8* wsh = (half8*)(ws + (size_t)tensor * 262144);
        half8* wsl = wsh + 8192;
        const int code = nt * 16 + l15;
        const float* src = cb + code * 128 + s * 32 + quad * 8;
        float4 z0 = *(const float4*)src;
        float4 z1 = *(const float4*)(src + 4);
        float zz[8] = {z0.x, z0.y, z0.z, z0.w, z1.x, z1.y, z1.z, z1.w};
        half8 h, l;
        float p = 0.0f;
        #pragma unroll
        for (int j = 0; j < 8; ++j) {
            _Float16 hi = (_Float16)zz[j];
            h[j] = hi;
            l[j] = (_Float16)((zz[j] - (float)hi) * 2048.0f);  // scaled: avoid f16 denormals
            p = fmaf(zz[j], zz[j], p);
        }
        wsh[(nt * 4 + s) * 64 + lane] = h;
        wsl[(nt * 4 + s) * 64 + lane] = l;
        // c2: reduce over quad within wave, then deterministic cross-wave (s) sum
        p += __shfl_xor(p, 16);
        p += __shfl_xor(p, 32);
        __shared__ float c2p[4][16];
        if (lane < 16) c2p[s][lane] = p;
        __syncthreads();
        if (t < 16)
            ((float*)(ws + WS_C2))[tensor * 512 + nt * 16 + t] =
                ((c2p[0][t] + c2p[1][t]) + c2p[2][t]) + c2p[3][t];
    } else {
        // zero scalar losses (4) + usage (1024): harness poisons d_out each call
        int i = (b - 64) * 256 + t;
        if (i < 1028) out[OUT_SC + i] = 0.0f;
    }
}

// Block: 256 threads (4 waves), 128 rows; wave: 32 rows (2 m-tiles of 16).
// Barrier-free K-loop: B-fragments streamed straight from L2 (fragment-ordered ws),
// double-buffered in registers. 24 MFMA per nt overlap next-nt prefetch.
// NO device atomics in this kernel: loss partials go to ws via plain stores
// (the former 16K same-cacheline atomicAdds were serviced ~40cyc each = ~273us,
// which matches the observed duration floor of every previous variant).
__global__ __launch_bounds__(256, 2)
void vq_main(const float* __restrict__ Kp, const float* __restrict__ Vp,
             const float* __restrict__ cb_k, const float* __restrict__ cb_v,
             float* __restrict__ out, char* __restrict__ ws) {
    __shared__ int   lds_idx[128];
    __shared__ float lds_loss[4];

    const int tid  = threadIdx.x;
    const int wave = tid >> 6;
    const int lane = tid & 63;
    const int quad = lane >> 4;
    const int l15  = lane & 15;
    const int tensor = blockIdx.y;

    const float* __restrict__ Z   = tensor ? Vp : Kp;
    const float* __restrict__ cbf = tensor ? cb_v : cb_k;
    const half8* __restrict__ gh  = (const half8*)(ws + (size_t)tensor * 262144);
    const half8* __restrict__ gl  = gh + 8192;
    const float* __restrict__ c2g = (const float*)(ws + WS_C2) + tensor * 512;
    int* __restrict__ idxg = (int*)(ws + WS_IDX) + tensor * R_TOT;
    float* __restrict__ lossp = (float*)(ws + WS_LOSS) + tensor * 2048;
    float* __restrict__ outz = out + (size_t)tensor * 16777216;

    const int blockRow = blockIdx.x * 128;
    const int waveRow  = blockRow + wave * 32;

    // ---- Phase A: load this wave's 32 rows, build A-frags (hi + scaled-lo), row z2 ----
    // (arithmetic order identical to round 1 -> bit-identical distances)
    half8 ah[2][4], al[2][4];
    float z2r[2][4];
    #pragma unroll
    for (int t = 0; t < 2; ++t) {
        const float* zp = Z + (size_t)(waveRow + t * 16 + l15) * 128;
        float zsq = 0.0f;
        #pragma unroll
        for (int s = 0; s < 4; ++s) {
            const float* p = zp + s * 32 + quad * 8;   // A[m=l15][k=quad*8+j], k-step s*32
            float4 z0 = *(const float4*)p;
            float4 z1 = *(const float4*)(p + 4);
            float zz[8] = {z0.x, z0.y, z0.z, z0.w, z1.x, z1.y, z1.z, z1.w};
            #pragma unroll
            for (int j = 0; j < 8; ++j) {
                _Float16 h = (_Float16)zz[j];
                ah[t][s][j] = h;
                al[t][s][j] = (_Float16)((zz[j] - (float)h) * 2048.0f);
                zsq = fmaf(zz[j], zz[j], zsq);
            }
        }
        zsq += __shfl_xor(zsq, 16);   // sum across quads -> full row z2 on every lane
        zsq += __shfl_xor(zsq, 32);
        #pragma unroll
        for (int r = 0; r < 4; ++r) z2r[t][r] = __shfl(zsq, quad * 4 + r);  // z2 of C-rows
    }

    float bd[2][4];
    int   bi[2][4];
    #pragma unroll
    for (int t = 0; t < 2; ++t)
        #pragma unroll
        for (int r = 0; r < 4; ++r) { bd[t][r] = 3.4e38f; bi[t][r] = 0; }

    // ---- K-loop over 32 n-tiles of 16 codes, register-double-buffered B ----
    half8 bh[2][4], bl[2][4];
    #pragma unroll
    for (int s = 0; s < 4; ++s) {
        bh[0][s] = gh[s * 64 + lane];
        bl[0][s] = gl[s * 64 + lane];
    }

    #pragma unroll 2
    for (int nt = 0; nt < 32; ++nt) {
        const int cur = nt & 1, nxt = cur ^ 1;
        if (nt < 31) {
            #pragma unroll
            for (int s = 0; s < 4; ++s) {
                bh[nxt][s] = gh[((nt + 1) * 4 + s) * 64 + lane];
                bl[nxt][s] = gl[((nt + 1) * 4 + s) * 64 + lane];
            }
        }
        const float c2v = c2g[nt * 16 + l15];
        floatx4 p10 = {0,0,0,0}, p11 = {0,0,0,0}, p20 = {0,0,0,0}, p21 = {0,0,0,0};
        #pragma unroll
        for (int s = 0; s < 4; ++s) {
            p10 = __builtin_amdgcn_mfma_f32_16x16x32_f16(ah[0][s], bh[cur][s], p10, 0, 0, 0);
            p11 = __builtin_amdgcn_mfma_f32_16x16x32_f16(ah[1][s], bh[cur][s], p11, 0, 0, 0);
            p20 = __builtin_amdgcn_mfma_f32_16x16x32_f16(al[0][s], bh[cur][s], p20, 0, 0, 0);
            p21 = __builtin_amdgcn_mfma_f32_16x16x32_f16(al[1][s], bh[cur][s], p21, 0, 0, 0);
            p20 = __builtin_amdgcn_mfma_f32_16x16x32_f16(ah[0][s], bl[cur][s], p20, 0, 0, 0);
            p21 = __builtin_amdgcn_mfma_f32_16x16x32_f16(ah[1][s], bl[cur][s], p21, 0, 0, 0);
        }
        const int codeg = nt * 16 + l15;
        // Emulate ref fp32 rounding: d = fl( fl(z2+c2) - 2*logit ); ties -> lower idx.
        #pragma unroll
        for (int r = 0; r < 4; ++r) {
            float lg0 = fmaf(p20[r], 0x1p-11f, p10[r]);
            float d0  = fmaf(-2.0f, lg0, z2r[0][r] + c2v);
            if (d0 < bd[0][r]) { bd[0][r] = d0; bi[0][r] = codeg; }
            float lg1 = fmaf(p21[r], 0x1p-11f, p11[r]);
            float d1  = fmaf(-2.0f, lg1, z2r[1][r] + c2v);
            if (d1 < bd[1][r]) { bd[1][r] = d1; bi[1][r] = codeg; }
        }
    }

    // ---- argmin across the 16 lanes sharing rows; loss = sum(best dist) ----
    float lp = 0.0f;
    #pragma unroll
    for (int t = 0; t < 2; ++t)
        #pragma unroll
        for (int r = 0; r < 4; ++r) {
            float d = bd[t][r];
            int   i = bi[t][r];
            #pragma unroll
            for (int off = 8; off; off >>= 1) {
                float od = __shfl_xor(d, off);
                int   oi = __shfl_xor(i, off);
                if (od < d || (od == d && oi < i)) { d = od; i = oi; }
            }
            if (l15 == 0) {
                lds_idx[wave * 32 + t * 16 + quad * 4 + r] = i;
                lp += d;
            }
        }
    lp += __shfl_xor(lp, 16);
    lp += __shfl_xor(lp, 32);
    if (lane == 0) lds_loss[wave] = lp;
    __syncthreads();                               // the only block barrier in the kernel

    if (tid == 0) {
        // per-block loss partial, plain store (no contention); scale 0.25/2^24
        float bsum = ((lds_loss[0] + lds_loss[1]) + lds_loss[2]) + lds_loss[3];
        lossp[blockIdx.x] = bsum * 0x1p-26f;
    }
    if (tid < 128) idxg[blockRow + tid] = lds_idx[tid];

    // ---- Phase C: gather codebook rows (bit-exact fp32 copies), coalesced stores ----
    #pragma unroll
    for (int g = 0; g < 16; ++g) {
        int rl  = g * 8 + (tid >> 5);
        int idx = lds_idx[rl];
        int col = (tid & 31) * 4;
        float4 v = *(const float4*)(cbf + idx * 128 + col);
        *(float4*)(outz + (size_t)(blockRow + rl) * 128 + col) = v;
    }
}

// blocks 0..15: usage histogram (8 segs per tensor, 16384 rows each).
// blocks 16,17: loss reduction for tensor 0/1 (plain stores, deterministic).
__global__ void vq_hist(const char* __restrict__ ws, float* __restrict__ out) {
    const int tid = threadIdx.x;                 // 256
    const int b = blockIdx.x;
    if (b < 16) {
        __shared__ int h[512];
        const int tensor = b >> 3;
        const int seg = b & 7;
        h[tid] = 0; h[tid + 256] = 0;
        __syncthreads();
        const int* p = (const int*)(ws + WS_IDX) + tensor * R_TOT + seg * 16384;
        #pragma unroll
        for (int r = 0; r < 64; ++r) atomicAdd(&h[p[r * 256 + tid]], 1);
        __syncthreads();
        int c0 = h[tid], c1 = h[tid + 256];
        // usage = count * 2^-17: exact scaled-integer fp32 sums (16 lines, low contention)
        if (c0) atomicAdd(&out[OUT_USE + tensor * 512 + tid], (float)c0 * 0x1p-17f);
        if (c1) atomicAdd(&out[OUT_USE + tensor * 512 + tid + 256], (float)c1 * 0x1p-17f);
    } else {
        const int tensor = b - 16;
        const float* lossp = (const float*)(ws + WS_LOSS) + tensor * 2048;
        float s = 0.0f;
        #pragma unroll
        for (int j = 0; j < 8; ++j) s += lossp[j * 256 + tid];
        #pragma unroll
        for (int off = 1; off < 64; off <<= 1) s += __shfl_xor(s, off);
        __shared__ float l4[4];
        if ((tid & 63) == 0) l4[tid >> 6] = s;
        __syncthreads();
        if (tid == 0) {
            float tot = ((l4[0] + l4[1]) + l4[2]) + l4[3];
            out[OUT_SC + tensor] = tot;          // beta * commit
            out[OUT_SC + 2 + tensor] = tot;      // gamma * embed (identical in eval)
        }
    }
}

extern "C" void kernel_launch(void* const* d_in, const int* in_sizes, int n_in,
                              void* d_out, int out_size, void* d_ws, size_t ws_size,
                              hipStream_t stream) {
    (void)in_sizes; (void)n_in; (void)out_size; (void)ws_size;
    const float* K   = (const float*)d_in[0];
    const float* V   = (const float*)d_in[1];
    const float* cbk = (const float*)d_in[2];
    const float* cbv = (const float*)d_in[3];
    float* out = (float*)d_out;
    char* ws = (char*)d_ws;
    hipLaunchKernelGGL(vq_init, dim3(69), dim3(256), 0, stream, cbk, cbv, out, ws);
    hipLaunchKernelGGL(vq_main, dim3(1024, 2), dim3(256), 0, stream, K, V, cbk, cbv, out, ws);
    hipLaunchKernelGGL(vq_hist, dim3(18), dim3(256), 0, stream, (const char*)ws, out);
}